// Round 12
// baseline (385.136 us; speedup 1.0000x reference)
//
#include <hip/hip_runtime.h>
#include <hip/hip_bf16.h>

typedef __hip_bfloat16 bf16;
typedef __attribute__((ext_vector_type(8))) short short8;
typedef __attribute__((ext_vector_type(8))) unsigned short u16x8;
typedef __attribute__((ext_vector_type(4))) float f32x4;

#define QL   2048
#define KLEN 2048
#define BATCH 2
#define EMB  1024
#define NH   16
#define HD   64
#define SPE  4095   // 2*KLEN - 1 pe rows (slice starts at pe row 1)

// ---------------------------------------------------------------------------
// data-driven dtype detection (in_sizes does NOT disambiguate f32 vs bf16 —
// round-3 ERRATA). Wave-parallel ballot version.
__device__ __forceinline__ int detect_f32_wave(const void* __restrict__ p) {
    const ushort4 v = ((const ushort4*)p)[threadIdx.x & 63];
    int c = 0;
    c += __popcll(__ballot(((v.x >> 7) & 0xFF) >= 0x8A));
    c += __popcll(__ballot(((v.y >> 7) & 0xFF) >= 0x8A));
    c += __popcll(__ballot(((v.z >> 7) & 0xFF) >= 0x8A));
    c += __popcll(__ballot(((v.w >> 7) & 0xFF) >= 0x8A));
    return c >= 8;   // >=8 of 256 elements with |x|>=2048/NaN/Inf -> f32
}

__device__ __forceinline__ ushort4 cvt4(const void* src, long u4i, int f32) {
    ushort4 o;
    if (f32) {
        float4 v = ((const float4*)src)[u4i];
        bf16 a = (bf16)v.x, b = (bf16)v.y, c = (bf16)v.z, e = (bf16)v.w;
        o.x = *(unsigned short*)&a; o.y = *(unsigned short*)&b;
        o.z = *(unsigned short*)&c; o.w = *(unsigned short*)&e;
    } else {
        o = ((const ushort4*)src)[u4i];
    }
    return o;
}

// weight + bias conversion ONLY (activation conversion fused into GEMM A-staging).
__global__ __launch_bounds__(256) void conv_w(
    const void* w0, const void* w1, const void* w2, const void* w3, const void* w4,
    const void* cb, const void* pb, bf16* __restrict__ wdst)
{
    const int t = threadIdx.x;
    const int bid = blockIdx.x;
    __shared__ int f32s;
    if (bid < 1280) {
        const int seg = bid >> 8, inner = bid & 255;
        const void* src = seg == 0 ? w0 : seg == 1 ? w1 : seg == 2 ? w2 : seg == 3 ? w3 : w4;
        bf16* d = wdst + (size_t)seg * 1048576;
        if (t < 64) { int r = detect_f32_wave(src); if (t == 0) f32s = r; }
        __syncthreads();
        const int f32 = f32s;
#pragma unroll
        for (int i = 0; i < 4; i++) {
            long u4i = (long)inner * 1024 + i * 256 + t;
            ((ushort4*)d)[u4i] = cvt4(src, u4i, f32);
        }
    } else {
        if (t < 64) { int r = detect_f32_wave(cb); if (t == 0) f32s = r; }
        __syncthreads();
        const int f32 = f32s;
        ((ushort4*)(wdst + 5242880))[t]        = cvt4(cb, t, f32);
        ((ushort4*)(wdst + 5242880 + 1024))[t] = cvt4(pb, t, f32);
    }
}

// ---------------------------------------------------------------------------
__device__ __forceinline__ void llds16(const bf16* g, bf16* l) {
    __builtin_amdgcn_global_load_lds(
        (const __attribute__((address_space(1))) void*)g,
        (__attribute__((address_space(3))) void*)l,
        16, 0, 0);
}

__device__ __forceinline__ short8 pack_f32x8(const float4& a, const float4& b) {
    short8 o; bf16 x;
    x = (bf16)a.x; o[0] = *(short*)&x;  x = (bf16)a.y; o[1] = *(short*)&x;
    x = (bf16)a.z; o[2] = *(short*)&x;  x = (bf16)a.w; o[3] = *(short*)&x;
    x = (bf16)b.x; o[4] = *(short*)&x;  x = (bf16)b.y; o[5] = *(short*)&x;
    x = (bf16)b.z; o[6] = *(short*)&x;  x = (bf16)b.w; o[7] = *(short*)&x;
    return o;
}

// ---------------------------------------------------------------------------
// K-loop v4 (r10, KEPT): 64x128 tile, BK=64, single buffer, 2-wait rhythm.
// ---------------------------------------------------------------------------
template<bool F32>
__device__ void gloop64(
    const void* Av, const bf16* W, int m0, int n0, int mode,
    bf16* Asd, bf16* Wsd,
    int t, int wm, int wn, int lm, int quad, f32x4 acc[2][4])
{
    long go[2];
#pragma unroll
    for (int i = 0; i < 2; i++) {
        int c = i * 256 + t, r = c >> 3, gc = (c & 7) ^ (r & 7);
        int ar = m0 + r;
        if (mode == 3) { ar = ar + 1; if (ar > 4095) ar = 4095; }  // pe shift; row 4095 output discarded
        go[i] = (long)ar * 1024 + gc * 8;
    }

#pragma unroll 1
    for (int k0 = 0; k0 < 1024; k0 += 64) {
        u16x8 au[2]; float4 a32[2][2];
#pragma unroll
        for (int i = 0; i < 2; i++) {
            long e = go[i] + k0;
            if (F32) {
                const float4* F = (const float4*)Av;
                a32[i][0] = F[e >> 2];
                a32[i][1] = F[(e >> 2) + 1];
            } else {
                au[i] = ((const u16x8*)Av)[e >> 3];
            }
        }
#pragma unroll
        for (int i = 0; i < 4; i++) {
            int c = i * 256 + t, r = c >> 3, gc = (c & 7) ^ (r & 7);
            llds16(W + (size_t)(n0 + r) * 1024 + k0 + gc * 8, Wsd + (c & ~63) * 8);
        }
        asm volatile("s_waitcnt vmcnt(0)" ::: "memory");
#pragma unroll
        for (int i = 0; i < 2; i++) {
            int c = i * 256 + t;
            short8 v;
            if (F32) v = pack_f32x8(a32[i][0], a32[i][1]);
            else     v = *(short8*)&au[i];
            *(short8*)&Asd[c * 8] = v;
        }
        asm volatile("s_waitcnt lgkmcnt(0)" ::: "memory");
        __builtin_amdgcn_s_barrier();
        __builtin_amdgcn_sched_barrier(0);

#pragma unroll
        for (int kk = 0; kk < 2; kk++) {
            short8 af[2], wf[4];
#pragma unroll
            for (int x = 0; x < 2; x++) {
                int ra = wm + x * 16 + lm;
                af[x] = *(const short8*)&Asd[ra * 64 + (((kk * 4 + quad) ^ (ra & 7)) * 8)];
            }
#pragma unroll
            for (int y = 0; y < 4; y++) {
                int rb = wn + y * 16 + lm;
                wf[y] = *(const short8*)&Wsd[rb * 64 + (((kk * 4 + quad) ^ (rb & 7)) * 8)];
            }
#pragma unroll
            for (int mt = 0; mt < 2; mt++)
#pragma unroll
                for (int nt = 0; nt < 4; nt++)
                    acc[mt][nt] = __builtin_amdgcn_mfma_f32_16x16x32_bf16(
                        af[mt], wf[nt], acc[mt][nt], 0, 0, 0);
        }
        __builtin_amdgcn_s_barrier();
    }
}

// ---------------------------------------------------------------------------
// GEMM v6 (r10) + DIAGNOSTIC rep param (r12): rep=2 repeats the K-loop with
// acc re-zeroed — idempotent (identical writes) but doubles kernel duration,
// surfacing the proj GEMM's counters in the top-5 (it has hidden just below
// attn's 122us for the whole session). rep=1 restores production behavior.
// ---------------------------------------------------------------------------
__global__ __launch_bounds__(256) void gemm_big(
    const void* __restrict__ Aq, const void* __restrict__ Ak,
    const void* __restrict__ Avv, const void* __restrict__ Ape,
    const bf16* __restrict__ ao, const bf16* __restrict__ wslab,
    bf16* __restrict__ qc, bf16* __restrict__ qp,
    bf16* __restrict__ kw, bf16* __restrict__ vw,
    bf16* __restrict__ kpos, float* __restrict__ outf, int mode_base, int rep)
{
    const int nwg = gridDim.x;
    const int d = blockIdx.x;
    const int g = (d & 7) * (nwg >> 3) + (d >> 3);   // bijective, nwg%8==0
    const int by = g & 7;
    const int bx = (g >> 3) & 63;
    const int bz = g >> 9;

    const int mode = mode_base + bz;
    const void* A = mode == 0 ? Aq : mode == 1 ? Ak : mode == 2 ? Avv :
                    mode == 3 ? Ape : (const void*)ao;
    const bf16* W = wslab + (size_t)mode * 1048576;

    __shared__ __align__(16) bf16 Asd[64 * 64];
    __shared__ __align__(16) bf16 Wsd[128 * 64];
    __shared__ int f32s;

    const int t = threadIdx.x;
    const int w = t >> 6, lane = t & 63, lm = lane & 15, quad = lane >> 4;
    const int m0 = bx * 64, n0 = by * 128;
    const int wm = (w & 1) * 32, wn = (w >> 1) * 64;

    if (t < 64) { int r = detect_f32_wave(A); if (t == 0) f32s = r; }
    __syncthreads();

    f32x4 acc[2][4];

#pragma unroll 1
    for (int rp = 0; rp < rep; ++rp) {
#pragma unroll
        for (int i = 0; i < 2; i++)
#pragma unroll
            for (int j = 0; j < 4; j++) acc[i][j] = (f32x4){0, 0, 0, 0};
        if (f32s) gloop64<true >(A, W, m0, n0, mode, Asd, Wsd, t, wm, wn, lm, quad, acc);
        else      gloop64<false>(A, W, m0, n0, mode, Asd, Wsd, t, wm, wn, lm, quad, acc);
        __syncthreads();   // all reads of Asd/Wsd done before next pass restages
    }

    const bf16* cbb = wslab + 5242880;
    const bf16* pbb = wslab + 5242880 + 1024;

#pragma unroll
    for (int mt = 0; mt < 2; mt++) {
#pragma unroll
        for (int nt = 0; nt < 4; nt++) {
#pragma unroll
            for (int r4 = 0; r4 < 4; r4++) {
                int row = m0 + wm + mt * 16 + quad * 4 + r4;
                int col = n0 + wn + nt * 16 + lm;
                float v = acc[mt][nt][r4];
                if (mode == 0) {
                    int l = row >> 1, b = row & 1;
                    int h = col >> 6, dd = col & 63;
                    size_t idx = ((size_t)(b * NH + h) * QL + l) * HD + dd;
                    qc[idx] = (bf16)(v + __bfloat162float(cbb[col]));
                    qp[idx] = (bf16)(v + __bfloat162float(pbb[col]));
                } else if (mode == 1) {
                    int l = row >> 1, b = row & 1;
                    int h = col >> 6, dd = col & 63;
                    kw[((size_t)(b * NH + h) * KLEN + l) * HD + dd] = (bf16)v;
                } else if (mode == 2) {
                    int l = row >> 1, b = row & 1;
                    int h = col >> 6, dd = col & 63;
                    vw[((size_t)(b * NH + h) * KLEN + l) * HD + dd] = (bf16)v;
                } else if (mode == 3) {
                    if (row < SPE) {
                        int h = col >> 6, dd = col & 63;
                        kpos[((size_t)h * SPE + row) * HD + dd] = (bf16)v;
                    }
                } else {
                    outf[(size_t)row * 1024 + col] = v;
                }
            }
        }
    }
}

// ---------------------------------------------------------------------------
// MFMA flash attention v6 (REVERTED to r10 — 121.7us proven; r11's Sc/Pt
// vectorization CONCLUDED: conflicts halved but time flat->worse, i.e. attn's
// limiter is NOT LDS instruction throughput; also LDS 54784 crossed the
// 3-blocks/CU boundary. Do not revisit score-matrix layout.)
// ---------------------------------------------------------------------------
#define NEG_INF (-1.0e30f)
#define SCL2 0.18033688011f   /* 64^-0.5 * log2(e) */

__global__ __launch_bounds__(256) void attn_mfma(
    const bf16* __restrict__ qc_g, const bf16* __restrict__ qp_g,
    const bf16* __restrict__ k_g,  const bf16* __restrict__ v_g,
    const bf16* __restrict__ kpos_g, bf16* __restrict__ ao)
{
    // ---- XCD swizzle: each XCD owns 4 (h,b) groups; heavy blocks first ----
    const int lin = blockIdx.x + (blockIdx.y << 6) + (blockIdx.z << 10);
    const int xcd = lin & 7, s = lin >> 3;
    const int g   = (xcd << 2) | (s >> 6);   // 0..31 (h,b) group
    const int u   = s & 63;
    const int bx  = 63 - u;                  // LPT: longest blocks first
    const int h   = g & 15;
    const int b   = g >> 4;
    const int q0  = bx * 32;

    const bf16* qc_bh  = qc_g + ((size_t)(b * NH + h) * QL) * HD;
    const bf16* qp_bh  = qp_g + ((size_t)(b * NH + h) * QL) * HD;
    const bf16* k_bh   = k_g  + ((size_t)(b * NH + h) * KLEN) * HD;
    const bf16* v_bh   = v_g  + ((size_t)(b * NH + h) * KLEN) * HD;
    const bf16* kpos_h = kpos_g + (size_t)h * SPE * HD;

    __shared__ __align__(16) bf16 K_s [64 * 64];
    __shared__ __align__(16) bf16 Kp_s[96 * 64];
    __shared__ __align__(16) bf16 Vt_s[64 * 64];     // [d][k], chunk-swizzled
    __shared__ __align__(16) bf16 Pb_s[32 * 64];
    __shared__ float Sc_s[32][69];
    __shared__ float Pt_s[32][98];                   // read stride 97: free
    __shared__ float arow_s[32];

    const int t = threadIdx.x;
    const int w = t >> 6, lane = t & 63, lm = lane & 15, quad = lane >> 4;

    const int sr = t >> 3;            // softmax row
    const int sc = (t & 7) * 8;       // softmax col chunk
    const int vrr = t >> 3, vch = t & 7;   // V staging: k-pair 2*vrr, d-chunk vch
    const int vkc = vrr >> 2;         // k-chunk of this thread's V pair

    const int mtc = w & 1;            // content/PV m-tile
    const int ntc = (w >> 1) * 2;     // content/PV n-tile base
    const int mtp = w >> 1;           // pos m-tile
    const int ntp = (w & 1) * 3;      // pos n-tile base

    float m_run = NEG_INF, l_part = 0.0f;
    f32x4 accO[2] = {{0,0,0,0},{0,0,0,0}};
    u16x8 vv0, vv1;

    const int nkt = (bx >> 1) + 1;

    // ---- Q fragments: loop-invariant, straight global -> registers ----
    short8 aQc0, aQc1, aQp0, aQp1;
    {
        const bf16* qr = qc_bh + (size_t)(q0 + mtc * 16 + lm) * HD;
        aQc0 = *(const short8*)(qr + quad * 8);
        aQc1 = *(const short8*)(qr + (4 + quad) * 8);
        const bf16* pr = qp_bh + (size_t)(q0 + mtp * 16 + lm) * HD;
        aQp0 = *(const short8*)(pr + quad * 8);
        aQp1 = *(const short8*)(pr + (4 + quad) * 8);
    }

    // ---- prologue: stage tile 0 ----
#pragma unroll
    for (int i = 0; i < 2; i++) {
        int c = i * 256 + t, r = c >> 3, ch = c & 7, gc = ch ^ (r & 7);
        llds16(k_bh + (size_t)r * HD + gc * 8, K_s + (c & ~63) * 8);
    }
    {
        const int s0 = 2016 - q0;
#pragma unroll
        for (int i = 0; i < 3; i++) {
            int c = i * 256 + t, r = c >> 3, ch = c & 7, gc = ch ^ (r & 7);
            llds16(kpos_h + (size_t)(s0 + r) * HD + gc * 8, Kp_s + (c & ~63) * 8);
        }
    }
    vv0 = *(const u16x8*)&v_bh[(size_t)(2 * vrr)     * HD + vch * 8];
    vv1 = *(const u16x8*)&v_bh[(size_t)(2 * vrr + 1) * HD + vch * 8];

    for (int kt = 0; kt < nkt; kt++) {
        const int k0 = kt * 64;

        __syncthreads();   // A: DMA drained; prev-iter PV reads of Vt done

        // ---- transpose-write V: slot = kc ^ (d>>3) ^ (d&7) ----
        {
            const int off = (2 * vrr) & 7;
#pragma unroll
            for (int j = 0; j < 8; j++) {
                unsigned int pair = (unsigned int)vv0[j] | ((unsigned int)vv1[j] << 16);
                int slot = vkc ^ vch ^ j;           // d>>3 = vch, d&7 = j
                *(unsigned int*)&Vt_s[(vch * 8 + j) * 64 + slot * 8 + off] = pair;
            }
        }

        // ---- content scores S = Qc K^T ----
        {
#pragma unroll
            for (int n = 0; n < 2; n++) {
                int rowB = (ntc + n) * 16 + lm;
                short8 b0 = *(const short8*)&K_s[rowB * 64 + ((quad)     ^ (rowB & 7)) * 8];
                short8 b1 = *(const short8*)&K_s[rowB * 64 + ((4 + quad) ^ (rowB & 7)) * 8];
                f32x4 acc = {0, 0, 0, 0};
                acc = __builtin_amdgcn_mfma_f32_16x16x32_bf16(aQc0, b0, acc, 0, 0, 0);
                acc = __builtin_amdgcn_mfma_f32_16x16x32_bf16(aQc1, b1, acc, 0, 0, 0);
#pragma unroll
                for (int r = 0; r < 4; r++)
                    Sc_s[mtc * 16 + quad * 4 + r][(ntc + n) * 16 + lm] = acc[r];
            }
        }
        // ---- pos band P~ = Qp Kp^T ----
        {
#pragma unroll
            for (int n = 0; n < 3; n++) {
                int rowB = (ntp + n) * 16 + lm;
                short8 b0 = *(const short8*)&Kp_s[rowB * 64 + ((quad)     ^ (rowB & 7)) * 8];
                short8 b1 = *(const short8*)&Kp_s[rowB * 64 + ((4 + quad) ^ (rowB & 7)) * 8];
                f32x4 acc = {0, 0, 0, 0};
                acc = __builtin_amdgcn_mfma_f32_16x16x32_bf16(aQp0, b0, acc, 0, 0, 0);
                acc = __builtin_amdgcn_mfma_f32_16x16x32_bf16(aQp1, b1, acc, 0, 0, 0);
#pragma unroll
                for (int r = 0; r < 4; r++)
                    Pt_s[mtp * 16 + quad * 4 + r][(ntp + n) * 16 + lm] = acc[r];
            }
        }

        __syncthreads();   // B: scores in LDS; K/Kp/Vt reads+writes done

        // ---- prefetch tile kt+1: issued BEFORE softmax, drains at next A ----
        if (kt + 1 < nkt) {
            const int k0n = k0 + 64;
            const int s0n = k0n - q0 + 2016;
#pragma unroll
            for (int i = 0; i < 2; i++) {
                int c = i * 256 + t, r = c >> 3, ch = c & 7, gc = ch ^ (r & 7);
                llds16(k_bh + (size_t)(k0n + r) * HD + gc * 8, K_s + (c & ~63) * 8);
            }
#pragma unroll
            for (int i = 0; i < 3; i++) {
                int c = i * 256 + t, r = c >> 3, ch = c & 7, gc = ch ^ (r & 7);
                llds16(kpos_h + (size_t)(s0n + r) * HD + gc * 8, Kp_s + (c & ~63) * 8);
            }
            vv0 = *(const u16x8*)&v_bh[(size_t)(k0n + 2 * vrr)     * HD + vch * 8];
            vv1 = *(const u16x8*)&v_bh[(size_t)(k0n + 2 * vrr + 1) * HD + vch * 8];
        }

        // ---- online softmax, exp2 domain: defer-max + deferred sum ----
        {
            float p[8];
            float pmax = NEG_INF;
#pragma unroll
            for (int j = 0; j < 8; j++) {
                int col = sc + j;
                float sv = (Sc_s[sr][col] + Pt_s[sr][col - sr + 31]) * SCL2;
                if (k0 + col > q0 + sr) sv = NEG_INF;
                p[j] = sv;
                pmax = fmaxf(pmax, sv);
            }
            float alpha = 1.0f;
            if (!__all(pmax <= m_run + 11.5f)) {
                float mx = pmax;
                mx = fmaxf(mx, __shfl_xor(mx, 1, 8));
                mx = fmaxf(mx, __shfl_xor(mx, 2, 8));
                mx = fmaxf(mx, __shfl_xor(mx, 4, 8));
                float mnew = fmaxf(m_run, mx);
                alpha = __builtin_amdgcn_exp2f(m_run - mnew);
                m_run = mnew;
            }
            float ls = 0.0f;
#pragma unroll
            for (int j = 0; j < 8; j++) {
                p[j] = __builtin_amdgcn_exp2f(p[j] - m_run);
                ls += p[j];
            }
            l_part = l_part * alpha + ls;
            if ((t & 7) == 0) arow_s[sr] = alpha;
            short8 pv;
#pragma unroll
            for (int j = 0; j < 8; j++) { bf16 x = (bf16)p[j]; pv[j] = *(short*)&x; }
            *(short8*)&Pb_s[sr * 64 + ((t & 7) ^ (sr & 7)) * 8] = pv;
        }

        // ---- C: LIGHT barrier — wait LDS ops only; keep prefetch DMA in flight
        asm volatile("s_waitcnt lgkmcnt(0)" ::: "memory");
        __builtin_amdgcn_s_barrier();
        __builtin_amdgcn_sched_barrier(0);

        // ---- O update: acc = alpha*acc + P V ----
        {
            float al[4];
#pragma unroll
            for (int r = 0; r < 4; r++) al[r] = arow_s[mtc * 16 + quad * 4 + r];
            int rowA = mtc * 16 + lm;
            short8 a0 = *(const short8*)&Pb_s[rowA * 64 + ((quad)     ^ (rowA & 7)) * 8];
            short8 a1 = *(const short8*)&Pb_s[rowA * 64 + ((4 + quad) ^ (rowA & 7)) * 8];
#pragma unroll
            for (int n = 0; n < 2; n++) {
                int d = (ntc + n) * 16 + lm;
                int ds = (d >> 3) ^ (d & 7);
                short8 b0 = *(const short8*)&Vt_s[d * 64 + ((quad     ^ ds)) * 8];
                short8 b1 = *(const short8*)&Vt_s[d * 64 + (((4 + quad) ^ ds)) * 8];
#pragma unroll
                for (int r = 0; r < 4; r++) accO[n][r] *= al[r];
                accO[n] = __builtin_amdgcn_mfma_f32_16x16x32_bf16(a0, b0, accO[n], 0, 0, 0);
                accO[n] = __builtin_amdgcn_mfma_f32_16x16x32_bf16(a1, b1, accO[n], 0, 0, 0);
            }
        }
    }

    // ---- epilogue: reduce per-thread partial l across the 8 threads/row ----
    l_part += __shfl_xor(l_part, 1, 8);
    l_part += __shfl_xor(l_part, 2, 8);
    l_part += __shfl_xor(l_part, 4, 8);

    __syncthreads();                       // protect arow before l broadcast
    if ((t & 7) == 0) arow_s[sr] = l_part;
    __syncthreads();

    float linv[4];
#pragma unroll
    for (int r = 0; r < 4; r++) linv[r] = 1.0f / arow_s[mtc * 16 + quad * 4 + r];
#pragma unroll
    for (int n = 0; n < 2; n++) {
#pragma unroll
        for (int r = 0; r < 4; r++) {
            int row = mtc * 16 + quad * 4 + r;
            ao[(((size_t)(q0 + row) * BATCH + b) * EMB) + h * HD + (ntc + n) * 16 + lm] =
                (bf16)(accO[n][r] * linv[r]);
        }
    }
}

// ---------------------------------------------------------------------------
extern "C" void kernel_launch(void* const* d_in, const int* in_sizes, int n_in,
                              void* d_out, int out_size, void* d_ws, size_t ws_size,
                              hipStream_t stream)
{
    const void* query = d_in[0];
    const void* key   = d_in[1];
    const void* value = d_in[2];
    const void* pe    = d_in[3];
    const void* w_q   = d_in[4];
    const void* w_k   = d_in[5];
    const void* w_v   = d_in[6];
    const void* w_kp  = d_in[7];
    const void* w_out = d_in[8];
    const void* cb    = d_in[9];
    const void* pb    = d_in[10];
    float* out = (float*)d_out;

    const size_t SLAB = 4194304;
    bf16* qc   = (bf16*)d_ws;          // S0
    bf16* qp   = qc + SLAB;            // S1
    bf16* kw   = qp + SLAB;            // S2
    bf16* vw   = kw + SLAB;            // S3
    bf16* kpos = vw + SLAB;            // S4
    bf16* ao   = kpos + SLAB;          // S5 (attention output)
    bf16* wqb  = ao + SLAB;            // S6: wq,wk,wv,wkp,wo,cb,pb

    dim3 blk(256);

    conv_w<<<dim3(1281), blk, 0, stream>>>(w_q, w_k, w_v, w_kp, w_out, cb, pb, wqb);

    // fused projections reading RAW inputs — DIAGNOSTIC rep=2 (idempotent
    // double K-loop) to surface proj counters in top-5 this round.
    gemm_big<<<dim3(2048), blk, 0, stream>>>(
        query, key, value, pe, nullptr, wqb, qc, qp, kw, vw, kpos, nullptr, 0, 2);

    attn_mfma<<<dim3(64, NH, BATCH), blk, 0, stream>>>(qc, qp, kw, vw, kpos, ao);

    // output projection (mode 4): ao @ wo^T -> f32 out (512 blocks, rep=1)
    gemm_big<<<dim3(512), blk, 0, stream>>>(
        query, key, value, pe, ao, wqb, qc, qp, kw, vw, kpos, out, 4, 1);
}

// Round 13
// 363.367 us; speedup vs baseline: 1.0599x; 1.0599x over previous
//
#include <hip/hip_runtime.h>
#include <hip/hip_bf16.h>

typedef __hip_bfloat16 bf16;
typedef __attribute__((ext_vector_type(8))) short short8;
typedef __attribute__((ext_vector_type(8))) unsigned short u16x8;
typedef __attribute__((ext_vector_type(4))) float f32x4;

#define QL   2048
#define KLEN 2048
#define BATCH 2
#define EMB  1024
#define NH   16
#define HD   64
#define SPE  4095   // 2*KLEN - 1 pe rows (slice starts at pe row 1)

// ---------------------------------------------------------------------------
// data-driven dtype detection (in_sizes does NOT disambiguate f32 vs bf16 —
// round-3 ERRATA). Wave-parallel; every wave computes the same answer from
// the same 256 elements, so NO shared-mem broadcast is needed (saves LDS).
__device__ __forceinline__ int detect_f32_wave(const void* __restrict__ p) {
    const ushort4 v = ((const ushort4*)p)[threadIdx.x & 63];
    int c = 0;
    c += __popcll(__ballot(((v.x >> 7) & 0xFF) >= 0x8A));
    c += __popcll(__ballot(((v.y >> 7) & 0xFF) >= 0x8A));
    c += __popcll(__ballot(((v.z >> 7) & 0xFF) >= 0x8A));
    c += __popcll(__ballot(((v.w >> 7) & 0xFF) >= 0x8A));
    return c >= 8;   // >=8 of 256 elements with |x|>=2048/NaN/Inf -> f32
}

__device__ __forceinline__ ushort4 cvt4(const void* src, long u4i, int f32) {
    ushort4 o;
    if (f32) {
        float4 v = ((const float4*)src)[u4i];
        bf16 a = (bf16)v.x, b = (bf16)v.y, c = (bf16)v.z, e = (bf16)v.w;
        o.x = *(unsigned short*)&a; o.y = *(unsigned short*)&b;
        o.z = *(unsigned short*)&c; o.w = *(unsigned short*)&e;
    } else {
        o = ((const ushort4*)src)[u4i];
    }
    return o;
}

// weight + bias conversion ONLY (activation conversion fused into GEMM A-staging).
__global__ __launch_bounds__(256) void conv_w(
    const void* w0, const void* w1, const void* w2, const void* w3, const void* w4,
    const void* cb, const void* pb, bf16* __restrict__ wdst)
{
    const int t = threadIdx.x;
    const int bid = blockIdx.x;
    if (bid < 1280) {
        const int seg = bid >> 8, inner = bid & 255;
        const void* src = seg == 0 ? w0 : seg == 1 ? w1 : seg == 2 ? w2 : seg == 3 ? w3 : w4;
        bf16* d = wdst + (size_t)seg * 1048576;
        const int f32 = detect_f32_wave(src);
#pragma unroll
        for (int i = 0; i < 4; i++) {
            long u4i = (long)inner * 1024 + i * 256 + t;
            ((ushort4*)d)[u4i] = cvt4(src, u4i, f32);
        }
    } else {
        const int f32 = detect_f32_wave(cb);
        ((ushort4*)(wdst + 5242880))[t]        = cvt4(cb, t, f32);
        ((ushort4*)(wdst + 5242880 + 1024))[t] = cvt4(pb, t, f32);
    }
}

// ---------------------------------------------------------------------------
__device__ __forceinline__ void llds16(const bf16* g, bf16* l) {
    __builtin_amdgcn_global_load_lds(
        (const __attribute__((address_space(1))) void*)g,
        (__attribute__((address_space(3))) void*)l,
        16, 0, 0);
}

__device__ __forceinline__ short8 pack_f32x8(const float4& a, const float4& b) {
    short8 o; bf16 x;
    x = (bf16)a.x; o[0] = *(short*)&x;  x = (bf16)a.y; o[1] = *(short*)&x;
    x = (bf16)a.z; o[2] = *(short*)&x;  x = (bf16)a.w; o[3] = *(short*)&x;
    x = (bf16)b.x; o[4] = *(short*)&x;  x = (bf16)b.y; o[5] = *(short*)&x;
    x = (bf16)b.z; o[6] = *(short*)&x;  x = (bf16)b.w; o[7] = *(short*)&x;
    return o;
}

// ---------------------------------------------------------------------------
// K-loop v5 (r13): 64x128 tile, BK=64, ONE-STEP LOOKAHEAD.
// r12 diagnostic (rep=2, surfaced counters): VGPR 56, conflicts 0, HBM 12%,
// MfmaUtil 19% -> per-step latency chain; the vmcnt(0)-after-issue drain
// kept loads out of flight during compute (~1 TB/s achieved on the cold
// 64MB A fetch). Fix: double-buffer W ONLY (A's next step lives in regs);
// issue A(i+1)+W(i+1) after the top barrier, BEFORE compute(i). The top
// drain then waits max(0, latency - compute) and loads fly during MFMA.
// Race audit: W(i+1) targets the buffer last read in compute(i-1) (reads
// retired before that iter's end barrier); Asd overwrite guarded by end
// barrier; top vmcnt(0) retires exactly {A(i) regs, W(i) DMA}.
// LDS 8K + 2x16K = 40960 -> EXACTLY 4 blocks/CU (163840/40960).
// ---------------------------------------------------------------------------
template<bool F32>
__device__ void gloop64(
    const void* Av, const bf16* W, int m0, int n0, int mode,
    bf16* Asd, bf16* Wsd,            // Wsd: [2][128*64]
    int t, int wm, int wn, int lm, int quad, f32x4 acc[2][4])
{
    long go[2];
#pragma unroll
    for (int i = 0; i < 2; i++) {
        int c = i * 256 + t, r = c >> 3, gc = (c & 7) ^ (r & 7);
        int ar = m0 + r;
        if (mode == 3) { ar = ar + 1; if (ar > 4095) ar = 4095; }  // pe shift; row 4095 output discarded
        go[i] = (long)ar * 1024 + gc * 8;
    }

    u16x8 auA[2], auB[2];
    float4 fA[2][2], fB[2][2];

    auto loadA = [&](int k0, u16x8 au[2], float4 a32[2][2]) {
#pragma unroll
        for (int i = 0; i < 2; i++) {
            long e = go[i] + k0;
            if (F32) {
                const float4* F = (const float4*)Av;
                a32[i][0] = F[e >> 2];
                a32[i][1] = F[(e >> 2) + 1];
            } else {
                au[i] = ((const u16x8*)Av)[e >> 3];
            }
        }
    };
    auto writeA = [&](u16x8 au[2], float4 a32[2][2]) {
#pragma unroll
        for (int i = 0; i < 2; i++) {
            int c = i * 256 + t;
            short8 v;
            if (F32) v = pack_f32x8(a32[i][0], a32[i][1]);
            else     v = *(short8*)&au[i];
            *(short8*)&Asd[c * 8] = v;
        }
    };
    auto stageW = [&](bf16* dst, int k0) {
#pragma unroll
        for (int i = 0; i < 4; i++) {
            int c = i * 256 + t, r = c >> 3, gc = (c & 7) ^ (r & 7);
            llds16(W + (size_t)(n0 + r) * 1024 + k0 + gc * 8, dst + (c & ~63) * 8);
        }
    };

    loadA(0, auA, fA);
    stageW(Wsd, 0);

#pragma unroll 1
    for (int it = 0; it < 16; ++it) {
        const int k0 = it * 64;
        bf16* Wc = Wsd + (it & 1) * (128 * 64);
        bf16* Wn = Wsd + ((it + 1) & 1) * (128 * 64);

        asm volatile("s_waitcnt vmcnt(0)" ::: "memory");   // A(it) regs + W(it) DMA
        if (it & 1) writeA(auB, fB); else writeA(auA, fA);
        asm volatile("s_waitcnt lgkmcnt(0)" ::: "memory");
        __builtin_amdgcn_s_barrier();                      // tile it visible
        __builtin_amdgcn_sched_barrier(0);

        if (it + 1 < 16) {                                 // prefetch it+1 early
            if (it & 1) loadA(k0 + 64, auA, fA);
            else        loadA(k0 + 64, auB, fB);
            stageW(Wn, k0 + 64);
        }

#pragma unroll
        for (int kk = 0; kk < 2; kk++) {
            short8 af[2], wf[4];
#pragma unroll
            for (int x = 0; x < 2; x++) {
                int ra = wm + x * 16 + lm;
                af[x] = *(const short8*)&Asd[ra * 64 + (((kk * 4 + quad) ^ (ra & 7)) * 8)];
            }
#pragma unroll
            for (int y = 0; y < 4; y++) {
                int rb = wn + y * 16 + lm;
                wf[y] = *(const short8*)&Wc[rb * 64 + (((kk * 4 + quad) ^ (rb & 7)) * 8)];
            }
#pragma unroll
            for (int mt = 0; mt < 2; mt++)
#pragma unroll
                for (int nt = 0; nt < 4; nt++)
                    acc[mt][nt] = __builtin_amdgcn_mfma_f32_16x16x32_bf16(
                        af[mt], wf[nt], acc[mt][nt], 0, 0, 0);
        }
        __builtin_amdgcn_s_barrier();                      // Asd/Wc reads done
    }
}

// ---------------------------------------------------------------------------
// GEMM v7: 64x128 tile, wave tile 32x64 (acc 2x4), BK=64, 4 blocks/CU.
// by-fastest tile order (r10, A-panel L2 reuse). Raw-input A with fused
// f32->bf16 conversion. mode: 0 q-proj(2 outs+biases), 1 k, 2 v, 3 pe, 4 out.
// ---------------------------------------------------------------------------
__global__ __launch_bounds__(256) void gemm_big(
    const void* __restrict__ Aq, const void* __restrict__ Ak,
    const void* __restrict__ Avv, const void* __restrict__ Ape,
    const bf16* __restrict__ ao, const bf16* __restrict__ wslab,
    bf16* __restrict__ qc, bf16* __restrict__ qp,
    bf16* __restrict__ kw, bf16* __restrict__ vw,
    bf16* __restrict__ kpos, float* __restrict__ outf, int mode_base)
{
    const int nwg = gridDim.x;
    const int d = blockIdx.x;
    const int g = (d & 7) * (nwg >> 3) + (d >> 3);   // bijective, nwg%8==0
    const int by = g & 7;
    const int bx = (g >> 3) & 63;
    const int bz = g >> 9;

    const int mode = mode_base + bz;
    const void* A = mode == 0 ? Aq : mode == 1 ? Ak : mode == 2 ? Avv :
                    mode == 3 ? Ape : (const void*)ao;
    const bf16* W = wslab + (size_t)mode * 1048576;

    __shared__ __align__(16) bf16 Asd[64 * 64];          //  8 KB
    __shared__ __align__(16) bf16 Wsd[2][128 * 64];      // 32 KB -> total 40960

    const int t = threadIdx.x;
    const int w = t >> 6, lane = t & 63, lm = lane & 15, quad = lane >> 4;
    const int m0 = bx * 64, n0 = by * 128;
    const int wm = (w & 1) * 32, wn = (w >> 1) * 64;

    const int f32 = detect_f32_wave(A);   // wave-uniform, identical across waves

    f32x4 acc[2][4] = {};

    if (f32) gloop64<true >(A, W, m0, n0, mode, Asd, &Wsd[0][0], t, wm, wn, lm, quad, acc);
    else     gloop64<false>(A, W, m0, n0, mode, Asd, &Wsd[0][0], t, wm, wn, lm, quad, acc);

    const bf16* cbb = wslab + 5242880;
    const bf16* pbb = wslab + 5242880 + 1024;

#pragma unroll
    for (int mt = 0; mt < 2; mt++) {
#pragma unroll
        for (int nt = 0; nt < 4; nt++) {
#pragma unroll
            for (int r4 = 0; r4 < 4; r4++) {
                int row = m0 + wm + mt * 16 + quad * 4 + r4;
                int col = n0 + wn + nt * 16 + lm;
                float v = acc[mt][nt][r4];
                if (mode == 0) {
                    int l = row >> 1, b = row & 1;
                    int h = col >> 6, dd = col & 63;
                    size_t idx = ((size_t)(b * NH + h) * QL + l) * HD + dd;
                    qc[idx] = (bf16)(v + __bfloat162float(cbb[col]));
                    qp[idx] = (bf16)(v + __bfloat162float(pbb[col]));
                } else if (mode == 1) {
                    int l = row >> 1, b = row & 1;
                    int h = col >> 6, dd = col & 63;
                    kw[((size_t)(b * NH + h) * KLEN + l) * HD + dd] = (bf16)v;
                } else if (mode == 2) {
                    int l = row >> 1, b = row & 1;
                    int h = col >> 6, dd = col & 63;
                    vw[((size_t)(b * NH + h) * KLEN + l) * HD + dd] = (bf16)v;
                } else if (mode == 3) {
                    if (row < SPE) {
                        int h = col >> 6, dd = col & 63;
                        kpos[((size_t)h * SPE + row) * HD + dd] = (bf16)v;
                    }
                } else {
                    outf[(size_t)row * 1024 + col] = v;
                }
            }
        }
    }
}

// ---------------------------------------------------------------------------
// MFMA flash attention v6 (r10, FROZEN at 121.7us):
//  - heavy-first (LPT) dispatch (r4/r5 A/B: +30% vs alternating).
//  - Vt slot = kc^(d>>3)^(d&7); Pt stride 98; exp2 softmax; 3 blocks/CU.
//  - r11 CONCLUDED: halving bank conflicts bought 0 time -> limiter is the
//    serial 3-barrier dependency chain, not LDS throughput. Frozen.
// ---------------------------------------------------------------------------
#define NEG_INF (-1.0e30f)
#define SCL2 0.18033688011f   /* 64^-0.5 * log2(e) */

__global__ __launch_bounds__(256) void attn_mfma(
    const bf16* __restrict__ qc_g, const bf16* __restrict__ qp_g,
    const bf16* __restrict__ k_g,  const bf16* __restrict__ v_g,
    const bf16* __restrict__ kpos_g, bf16* __restrict__ ao)
{
    // ---- XCD swizzle: each XCD owns 4 (h,b) groups; heavy blocks first ----
    const int lin = blockIdx.x + (blockIdx.y << 6) + (blockIdx.z << 10);
    const int xcd = lin & 7, s = lin >> 3;
    const int g   = (xcd << 2) | (s >> 6);   // 0..31 (h,b) group
    const int u   = s & 63;
    const int bx  = 63 - u;                  // LPT: longest blocks first
    const int h   = g & 15;
    const int b   = g >> 4;
    const int q0  = bx * 32;

    const bf16* qc_bh  = qc_g + ((size_t)(b * NH + h) * QL) * HD;
    const bf16* qp_bh  = qp_g + ((size_t)(b * NH + h) * QL) * HD;
    const bf16* k_bh   = k_g  + ((size_t)(b * NH + h) * KLEN) * HD;
    const bf16* v_bh   = v_g  + ((size_t)(b * NH + h) * KLEN) * HD;
    const bf16* kpos_h = kpos_g + (size_t)h * SPE * HD;

    __shared__ __align__(16) bf16 K_s [64 * 64];
    __shared__ __align__(16) bf16 Kp_s[96 * 64];
    __shared__ __align__(16) bf16 Vt_s[64 * 64];     // [d][k], chunk-swizzled
    __shared__ __align__(16) bf16 Pb_s[32 * 64];
    __shared__ float Sc_s[32][69];
    __shared__ float Pt_s[32][98];                   // read stride 97: free
    __shared__ float arow_s[32];

    const int t = threadIdx.x;
    const int w = t >> 6, lane = t & 63, lm = lane & 15, quad = lane >> 4;

    const int sr = t >> 3;            // softmax row
    const int sc = (t & 7) * 8;       // softmax col chunk
    const int vrr = t >> 3, vch = t & 7;   // V staging: k-pair 2*vrr, d-chunk vch
    const int vkc = vrr >> 2;         // k-chunk of this thread's V pair

    const int mtc = w & 1;            // content/PV m-tile
    const int ntc = (w >> 1) * 2;     // content/PV n-tile base
    const int mtp = w >> 1;           // pos m-tile
    const int ntp = (w & 1) * 3;      // pos n-tile base

    float m_run = NEG_INF, l_part = 0.0f;
    f32x4 accO[2] = {{0,0,0,0},{0,0,0,0}};
    u16x8 vv0, vv1;

    const int nkt = (bx >> 1) + 1;

    // ---- Q fragments: loop-invariant, straight global -> registers ----
    short8 aQc0, aQc1, aQp0, aQp1;
    {
        const bf16* qr = qc_bh + (size_t)(q0 + mtc * 16 + lm) * HD;
        aQc0 = *(const short8*)(qr + quad * 8);
        aQc1 = *(const short8*)(qr + (4 + quad) * 8);
        const bf16* pr = qp_bh + (size_t)(q0 + mtp * 16 + lm) * HD;
        aQp0 = *(const short8*)(pr + quad * 8);
        aQp1 = *(const short8*)(pr + (4 + quad) * 8);
    }

    // ---- prologue: stage tile 0 ----
#pragma unroll
    for (int i = 0; i < 2; i++) {
        int c = i * 256 + t, r = c >> 3, ch = c & 7, gc = ch ^ (r & 7);
        llds16(k_bh + (size_t)r * HD + gc * 8, K_s + (c & ~63) * 8);
    }
    {
        const int s0 = 2016 - q0;
#pragma unroll
        for (int i = 0; i < 3; i++) {
            int c = i * 256 + t, r = c >> 3, ch = c & 7, gc = ch ^ (r & 7);
            llds16(kpos_h + (size_t)(s0 + r) * HD + gc * 8, Kp_s + (c & ~63) * 8);
        }
    }
    vv0 = *(const u16x8*)&v_bh[(size_t)(2 * vrr)     * HD + vch * 8];
    vv1 = *(const u16x8*)&v_bh[(size_t)(2 * vrr + 1) * HD + vch * 8];

    for (int kt = 0; kt < nkt; kt++) {
        const int k0 = kt * 64;

        __syncthreads();   // A: DMA drained; prev-iter PV reads of Vt done

        // ---- transpose-write V: slot = kc ^ (d>>3) ^ (d&7) ----
        {
            const int off = (2 * vrr) & 7;
#pragma unroll
            for (int j = 0; j < 8; j++) {
                unsigned int pair = (unsigned int)vv0[j] | ((unsigned int)vv1[j] << 16);
                int slot = vkc ^ vch ^ j;           // d>>3 = vch, d&7 = j
                *(unsigned int*)&Vt_s[(vch * 8 + j) * 64 + slot * 8 + off] = pair;
            }
        }

        // ---- content scores S = Qc K^T ----
        {
#pragma unroll
            for (int n = 0; n < 2; n++) {
                int rowB = (ntc + n) * 16 + lm;
                short8 b0 = *(const short8*)&K_s[rowB * 64 + ((quad)     ^ (rowB & 7)) * 8];
                short8 b1 = *(const short8*)&K_s[rowB * 64 + ((4 + quad) ^ (rowB & 7)) * 8];
                f32x4 acc = {0, 0, 0, 0};
                acc = __builtin_amdgcn_mfma_f32_16x16x32_bf16(aQc0, b0, acc, 0, 0, 0);
                acc = __builtin_amdgcn_mfma_f32_16x16x32_bf16(aQc1, b1, acc, 0, 0, 0);
#pragma unroll
                for (int r = 0; r < 4; r++)
                    Sc_s[mtc * 16 + quad * 4 + r][(ntc + n) * 16 + lm] = acc[r];
            }
        }
        // ---- pos band P~ = Qp Kp^T ----
        {
#pragma unroll
            for (int n = 0; n < 3; n++) {
                int rowB = (ntp + n) * 16 + lm;
                short8 b0 = *(const short8*)&Kp_s[rowB * 64 + ((quad)     ^ (rowB & 7)) * 8];
                short8 b1 = *(const short8*)&Kp_s[rowB * 64 + ((4 + quad) ^ (rowB & 7)) * 8];
                f32x4 acc = {0, 0, 0, 0};
                acc = __builtin_amdgcn_mfma_f32_16x16x32_bf16(aQp0, b0, acc, 0, 0, 0);
                acc = __builtin_amdgcn_mfma_f32_16x16x32_bf16(aQp1, b1, acc, 0, 0, 0);
#pragma unroll
                for (int r = 0; r < 4; r++)
                    Pt_s[mtp * 16 + quad * 4 + r][(ntp + n) * 16 + lm] = acc[r];
            }
        }

        __syncthreads();   // B: scores in LDS; K/Kp/Vt reads+writes done

        // ---- prefetch tile kt+1: issued BEFORE softmax, drains at next A ----
        if (kt + 1 < nkt) {
            const int k0n = k0 + 64;
            const int s0n = k0n - q0 + 2016;
#pragma unroll
            for (int i = 0; i < 2; i++) {
                int c = i * 256 + t, r = c >> 3, ch = c & 7, gc = ch ^ (r & 7);
                llds16(k_bh + (size_t)(k0n + r) * HD + gc * 8, K_s + (c & ~63) * 8);
            }
#pragma unroll
            for (int i = 0; i < 3; i++) {
                int c = i * 256 + t, r = c >> 3, ch = c & 7, gc = ch ^ (r & 7);
                llds16(kpos_h + (size_t)(s0n + r) * HD + gc * 8, Kp_s + (c & ~63) * 8);
            }
            vv0 = *(const u16x8*)&v_bh[(size_t)(k0n + 2 * vrr)     * HD + vch * 8];
            vv1 = *(const u16x8*)&v_bh[(size_t)(k0n + 2 * vrr + 1) * HD + vch * 8];
        }

        // ---- online softmax, exp2 domain: defer-max + deferred sum ----
        {
            float p[8];
            float pmax = NEG_INF;
#pragma unroll
            for (int j = 0; j < 8; j++) {
                int col = sc + j;
                float sv = (Sc_s[sr][col] + Pt_s[sr][col - sr + 31]) * SCL2;
                if (k0 + col > q0 + sr) sv = NEG_INF;
                p[j] = sv;
                pmax = fmaxf(pmax, sv);
            }
            float alpha = 1.0f;
            if (!__all(pmax <= m_run + 11.5f)) {
                float mx = pmax;
                mx = fmaxf(mx, __shfl_xor(mx, 1, 8));
                mx = fmaxf(mx, __shfl_xor(mx, 2, 8));
                mx = fmaxf(mx, __shfl_xor(mx, 4, 8));
                float mnew = fmaxf(m_run, mx);
                alpha = __builtin_amdgcn_exp2f(m_run - mnew);
                m_run = mnew;
            }
            float ls = 0.0f;
#pragma unroll
            for (int j = 0; j < 8; j++) {
                p[j] = __builtin_amdgcn_exp2f(p[j] - m_run);
                ls += p[j];
            }
            l_part = l_part * alpha + ls;
            if ((t & 7) == 0) arow_s[sr] = alpha;
            short8 pv;
#pragma unroll
            for (int j = 0; j < 8; j++) { bf16 x = (bf16)p[j]; pv[j] = *(short*)&x; }
            *(short8*)&Pb_s[sr * 64 + ((t & 7) ^ (sr & 7)) * 8] = pv;
        }

        // ---- C: LIGHT barrier — wait LDS ops only; keep prefetch DMA in flight
        asm volatile("s_waitcnt lgkmcnt(0)" ::: "memory");
        __builtin_amdgcn_s_barrier();
        __builtin_amdgcn_sched_barrier(0);

        // ---- O update: acc = alpha*acc + P V ----
        {
            float al[4];
#pragma unroll
            for (int r = 0; r < 4; r++) al[r] = arow_s[mtc * 16 + quad * 4 + r];
            int rowA = mtc * 16 + lm;
            short8 a0 = *(const short8*)&Pb_s[rowA * 64 + ((quad)     ^ (rowA & 7)) * 8];
            short8 a1 = *(const short8*)&Pb_s[rowA * 64 + ((4 + quad) ^ (rowA & 7)) * 8];
#pragma unroll
            for (int n = 0; n < 2; n++) {
                int d = (ntc + n) * 16 + lm;
                int ds = (d >> 3) ^ (d & 7);
                short8 b0 = *(const short8*)&Vt_s[d * 64 + ((quad     ^ ds)) * 8];
                short8 b1 = *(const short8*)&Vt_s[d * 64 + (((4 + quad) ^ ds)) * 8];
#pragma unroll
                for (int r = 0; r < 4; r++) accO[n][r] *= al[r];
                accO[n] = __builtin_amdgcn_mfma_f32_16x16x32_bf16(a0, b0, accO[n], 0, 0, 0);
                accO[n] = __builtin_amdgcn_mfma_f32_16x16x32_bf16(a1, b1, accO[n], 0, 0, 0);
            }
        }
    }

    // ---- epilogue: reduce per-thread partial l across the 8 threads/row ----
    l_part += __shfl_xor(l_part, 1, 8);
    l_part += __shfl_xor(l_part, 2, 8);
    l_part += __shfl_xor(l_part, 4, 8);

    __syncthreads();                       // protect arow before l broadcast
    if ((t & 7) == 0) arow_s[sr] = l_part;
    __syncthreads();

    float linv[4];
#pragma unroll
    for (int r = 0; r < 4; r++) linv[r] = 1.0f / arow_s[mtc * 16 + quad * 4 + r];
#pragma unroll
    for (int n = 0; n < 2; n++) {
#pragma unroll
        for (int r = 0; r < 4; r++) {
            int row = mtc * 16 + quad * 4 + r;
            ao[(((size_t)(q0 + row) * BATCH + b) * EMB) + h * HD + (ntc + n) * 16 + lm] =
                (bf16)(accO[n][r] * linv[r]);
        }
    }
}

// ---------------------------------------------------------------------------
extern "C" void kernel_launch(void* const* d_in, const int* in_sizes, int n_in,
                              void* d_out, int out_size, void* d_ws, size_t ws_size,
                              hipStream_t stream)
{
    const void* query = d_in[0];
    const void* key   = d_in[1];
    const void* value = d_in[2];
    const void* pe    = d_in[3];
    const void* w_q   = d_in[4];
    const void* w_k   = d_in[5];
    const void* w_v   = d_in[6];
    const void* w_kp  = d_in[7];
    const void* w_out = d_in[8];
    const void* cb    = d_in[9];
    const void* pb    = d_in[10];
    float* out = (float*)d_out;

    const size_t SLAB = 4194304;
    bf16* qc   = (bf16*)d_ws;          // S0
    bf16* qp   = qc + SLAB;            // S1
    bf16* kw   = qp + SLAB;            // S2
    bf16* vw   = kw + SLAB;            // S3
    bf16* kpos = vw + SLAB;            // S4
    bf16* ao   = kpos + SLAB;          // S5 (attention output)
    bf16* wqb  = ao + SLAB;            // S6: wq,wk,wv,wkp,wo,cb,pb

    dim3 blk(256);

    conv_w<<<dim3(1281), blk, 0, stream>>>(w_q, w_k, w_v, w_kp, w_out, cb, pb, wqb);

    // fused projections reading RAW inputs: q (2 outs + biases), k, v, pe
    gemm_big<<<dim3(2048), blk, 0, stream>>>(
        query, key, value, pe, nullptr, wqb, qc, qp, kw, vw, kpos, nullptr, 0);

    attn_mfma<<<dim3(64, NH, BATCH), blk, 0, stream>>>(qc, qp, kw, vw, kpos, ao);

    // output projection (mode 4): ao @ wo^T -> f32 out (512 blocks)
    gemm_big<<<dim3(512), blk, 0, stream>>>(
        query, key, value, pe, ao, wqb, qc, qp, kw, vw, kpos, out, 4);
}

// Round 14
// 341.580 us; speedup vs baseline: 1.1275x; 1.0638x over previous
//
#include <hip/hip_runtime.h>
#include <hip/hip_bf16.h>

typedef __hip_bfloat16 bf16;
typedef __attribute__((ext_vector_type(8))) short short8;
typedef __attribute__((ext_vector_type(8))) unsigned short u16x8;
typedef __attribute__((ext_vector_type(4))) float f32x4;

#define QL   2048
#define KLEN 2048
#define BATCH 2
#define EMB  1024
#define NH   16
#define HD   64
#define SPE  4095   // 2*KLEN - 1 pe rows (slice starts at pe row 1)

// ---------------------------------------------------------------------------
// data-driven dtype detection (in_sizes does NOT disambiguate f32 vs bf16 —
// round-3 ERRATA). Wave-parallel; identical answer in every wave, no LDS
// broadcast needed (r13-verified).
__device__ __forceinline__ int detect_f32_wave(const void* __restrict__ p) {
    const ushort4 v = ((const ushort4*)p)[threadIdx.x & 63];
    int c = 0;
    c += __popcll(__ballot(((v.x >> 7) & 0xFF) >= 0x8A));
    c += __popcll(__ballot(((v.y >> 7) & 0xFF) >= 0x8A));
    c += __popcll(__ballot(((v.z >> 7) & 0xFF) >= 0x8A));
    c += __popcll(__ballot(((v.w >> 7) & 0xFF) >= 0x8A));
    return c >= 8;   // >=8 of 256 elements with |x|>=2048/NaN/Inf -> f32
}

__device__ __forceinline__ ushort4 cvt4(const void* src, long u4i, int f32) {
    ushort4 o;
    if (f32) {
        float4 v = ((const float4*)src)[u4i];
        bf16 a = (bf16)v.x, b = (bf16)v.y, c = (bf16)v.z, e = (bf16)v.w;
        o.x = *(unsigned short*)&a; o.y = *(unsigned short*)&b;
        o.z = *(unsigned short*)&c; o.w = *(unsigned short*)&e;
    } else {
        o = ((const ushort4*)src)[u4i];
    }
    return o;
}

// weight + bias conversion ONLY (activation conversion fused into GEMM A-staging).
__global__ __launch_bounds__(256) void conv_w(
    const void* w0, const void* w1, const void* w2, const void* w3, const void* w4,
    const void* cb, const void* pb, bf16* __restrict__ wdst)
{
    const int t = threadIdx.x;
    const int bid = blockIdx.x;
    if (bid < 1280) {
        const int seg = bid >> 8, inner = bid & 255;
        const void* src = seg == 0 ? w0 : seg == 1 ? w1 : seg == 2 ? w2 : seg == 3 ? w3 : w4;
        bf16* d = wdst + (size_t)seg * 1048576;
        const int f32 = detect_f32_wave(src);
#pragma unroll
        for (int i = 0; i < 4; i++) {
            long u4i = (long)inner * 1024 + i * 256 + t;
            ((ushort4*)d)[u4i] = cvt4(src, u4i, f32);
        }
    } else {
        const int f32 = detect_f32_wave(cb);
        ((ushort4*)(wdst + 5242880))[t]        = cvt4(cb, t, f32);
        ((ushort4*)(wdst + 5242880 + 1024))[t] = cvt4(pb, t, f32);
    }
}

// ---------------------------------------------------------------------------
__device__ __forceinline__ void llds16(const bf16* g, bf16* l) {
    __builtin_amdgcn_global_load_lds(
        (const __attribute__((address_space(1))) void*)g,
        (__attribute__((address_space(3))) void*)l,
        16, 0, 0);
}

__device__ __forceinline__ short8 pack_f32x8(const float4& a, const float4& b) {
    short8 o; bf16 x;
    x = (bf16)a.x; o[0] = *(short*)&x;  x = (bf16)a.y; o[1] = *(short*)&x;
    x = (bf16)a.z; o[2] = *(short*)&x;  x = (bf16)a.w; o[3] = *(short*)&x;
    x = (bf16)b.x; o[4] = *(short*)&x;  x = (bf16)b.y; o[5] = *(short*)&x;
    x = (bf16)b.z; o[6] = *(short*)&x;  x = (bf16)b.w; o[7] = *(short*)&x;
    return o;
}

// ---------------------------------------------------------------------------
// K-loop v4 (r10, PROVEN BEST — restored verbatim): 64x128 tile, BK=64,
// single buffer, simple 2-wait rhythm, 6 blocks/CU.
// SESSION CONCLUSIONS (do not revisit):
//  - r8 (3-buf counted vmcnt, 2/CU) and r13 (W-dbuf lookahead-1, 4/CU) both
//    REGRESS: one K-step of compute (~200cy) << HBM latency (~900cy), so
//    lookahead-1 hides little while the LDS cost drops occupancy. At this
//    shape TLP (6 blocks/CU) > software pipelining.
//  - by-fastest tile order (A-panel L2 reuse) is what fixed the ~4x A
//    re-read queue saturation (r10: 359->345).
// ---------------------------------------------------------------------------
template<bool F32>
__device__ void gloop64(
    const void* Av, const bf16* W, int m0, int n0, int mode,
    bf16* Asd, bf16* Wsd,
    int t, int wm, int wn, int lm, int quad, f32x4 acc[2][4])
{
    long go[2];
#pragma unroll
    for (int i = 0; i < 2; i++) {
        int c = i * 256 + t, r = c >> 3, gc = (c & 7) ^ (r & 7);
        int ar = m0 + r;
        if (mode == 3) { ar = ar + 1; if (ar > 4095) ar = 4095; }  // pe shift; row 4095 output discarded
        go[i] = (long)ar * 1024 + gc * 8;
    }

#pragma unroll 1
    for (int k0 = 0; k0 < 1024; k0 += 64) {
        u16x8 au[2]; float4 a32[2][2];
#pragma unroll
        for (int i = 0; i < 2; i++) {
            long e = go[i] + k0;
            if (F32) {
                const float4* F = (const float4*)Av;
                a32[i][0] = F[e >> 2];
                a32[i][1] = F[(e >> 2) + 1];
            } else {
                au[i] = ((const u16x8*)Av)[e >> 3];
            }
        }
#pragma unroll
        for (int i = 0; i < 4; i++) {
            int c = i * 256 + t, r = c >> 3, gc = (c & 7) ^ (r & 7);
            llds16(W + (size_t)(n0 + r) * 1024 + k0 + gc * 8, Wsd + (c & ~63) * 8);
        }
        asm volatile("s_waitcnt vmcnt(0)" ::: "memory");
#pragma unroll
        for (int i = 0; i < 2; i++) {
            int c = i * 256 + t;
            short8 v;
            if (F32) v = pack_f32x8(a32[i][0], a32[i][1]);
            else     v = *(short8*)&au[i];
            *(short8*)&Asd[c * 8] = v;
        }
        asm volatile("s_waitcnt lgkmcnt(0)" ::: "memory");
        __builtin_amdgcn_s_barrier();
        __builtin_amdgcn_sched_barrier(0);

#pragma unroll
        for (int kk = 0; kk < 2; kk++) {
            short8 af[2], wf[4];
#pragma unroll
            for (int x = 0; x < 2; x++) {
                int ra = wm + x * 16 + lm;
                af[x] = *(const short8*)&Asd[ra * 64 + (((kk * 4 + quad) ^ (ra & 7)) * 8)];
            }
#pragma unroll
            for (int y = 0; y < 4; y++) {
                int rb = wn + y * 16 + lm;
                wf[y] = *(const short8*)&Wsd[rb * 64 + (((kk * 4 + quad) ^ (rb & 7)) * 8)];
            }
#pragma unroll
            for (int mt = 0; mt < 2; mt++)
#pragma unroll
                for (int nt = 0; nt < 4; nt++)
                    acc[mt][nt] = __builtin_amdgcn_mfma_f32_16x16x32_bf16(
                        af[mt], wf[nt], acc[mt][nt], 0, 0, 0);
        }
        __builtin_amdgcn_s_barrier();
    }
}

// ---------------------------------------------------------------------------
// GEMM v6 (r10, restored): 64x128 tile, wave tile 32x64 (acc 2x4), BK=64.
// LDS 24KB -> 6 blocks/CU. by-fastest tile order within each XCD.
// mode = mode_base + g>>9: 0 q-proj (2 outs + biases), 1 k, 2 v, 3 pe, 4 out.
// ---------------------------------------------------------------------------
__global__ __launch_bounds__(256) void gemm_big(
    const void* __restrict__ Aq, const void* __restrict__ Ak,
    const void* __restrict__ Avv, const void* __restrict__ Ape,
    const bf16* __restrict__ ao, const bf16* __restrict__ wslab,
    bf16* __restrict__ qc, bf16* __restrict__ qp,
    bf16* __restrict__ kw, bf16* __restrict__ vw,
    bf16* __restrict__ kpos, float* __restrict__ outf, int mode_base)
{
    const int nwg = gridDim.x;
    const int d = blockIdx.x;
    const int g = (d & 7) * (nwg >> 3) + (d >> 3);   // bijective, nwg%8==0
    const int by = g & 7;
    const int bx = (g >> 3) & 63;
    const int bz = g >> 9;

    const int mode = mode_base + bz;
    const void* A = mode == 0 ? Aq : mode == 1 ? Ak : mode == 2 ? Avv :
                    mode == 3 ? Ape : (const void*)ao;
    const bf16* W = wslab + (size_t)mode * 1048576;

    __shared__ __align__(16) bf16 Asd[64 * 64];
    __shared__ __align__(16) bf16 Wsd[128 * 64];

    const int t = threadIdx.x;
    const int w = t >> 6, lane = t & 63, lm = lane & 15, quad = lane >> 4;
    const int m0 = bx * 64, n0 = by * 128;
    const int wm = (w & 1) * 32, wn = (w >> 1) * 64;

    const int f32 = detect_f32_wave(A);   // wave-uniform, identical across waves

    f32x4 acc[2][4] = {};

    if (f32) gloop64<true >(A, W, m0, n0, mode, Asd, Wsd, t, wm, wn, lm, quad, acc);
    else     gloop64<false>(A, W, m0, n0, mode, Asd, Wsd, t, wm, wn, lm, quad, acc);

    const bf16* cbb = wslab + 5242880;
    const bf16* pbb = wslab + 5242880 + 1024;

#pragma unroll
    for (int mt = 0; mt < 2; mt++) {
#pragma unroll
        for (int nt = 0; nt < 4; nt++) {
#pragma unroll
            for (int r4 = 0; r4 < 4; r4++) {
                int row = m0 + wm + mt * 16 + quad * 4 + r4;
                int col = n0 + wn + nt * 16 + lm;
                float v = acc[mt][nt][r4];
                if (mode == 0) {
                    int l = row >> 1, b = row & 1;
                    int h = col >> 6, dd = col & 63;
                    size_t idx = ((size_t)(b * NH + h) * QL + l) * HD + dd;
                    qc[idx] = (bf16)(v + __bfloat162float(cbb[col]));
                    qp[idx] = (bf16)(v + __bfloat162float(pbb[col]));
                } else if (mode == 1) {
                    int l = row >> 1, b = row & 1;
                    int h = col >> 6, dd = col & 63;
                    kw[((size_t)(b * NH + h) * KLEN + l) * HD + dd] = (bf16)v;
                } else if (mode == 2) {
                    int l = row >> 1, b = row & 1;
                    int h = col >> 6, dd = col & 63;
                    vw[((size_t)(b * NH + h) * KLEN + l) * HD + dd] = (bf16)v;
                } else if (mode == 3) {
                    if (row < SPE) {
                        int h = col >> 6, dd = col & 63;
                        kpos[((size_t)h * SPE + row) * HD + dd] = (bf16)v;
                    }
                } else {
                    outf[(size_t)row * 1024 + col] = v;
                }
            }
        }
    }
}

// ---------------------------------------------------------------------------
// MFMA flash attention v6 (r10, FROZEN at 121.7us):
//  - heavy-first (LPT) dispatch (r4/r5 A/B: +30% vs alternating).
//  - Vt slot = kc^(d>>3)^(d&7); Pt stride 98; exp2 softmax; 3 blocks/CU.
//  - r5 audit: residual SQ_LDS_BANK_CONFLICT is the wave64 2-lanes/bank floor.
//  - r11 CONCLUDED: halving bank conflicts bought 0 time -> limiter is the
//    serial 3-barrier dependency chain, not LDS throughput. Frozen.
// ---------------------------------------------------------------------------
#define NEG_INF (-1.0e30f)
#define SCL2 0.18033688011f   /* 64^-0.5 * log2(e) */

__global__ __launch_bounds__(256) void attn_mfma(
    const bf16* __restrict__ qc_g, const bf16* __restrict__ qp_g,
    const bf16* __restrict__ k_g,  const bf16* __restrict__ v_g,
    const bf16* __restrict__ kpos_g, bf16* __restrict__ ao)
{
    // ---- XCD swizzle: each XCD owns 4 (h,b) groups; heavy blocks first ----
    const int lin = blockIdx.x + (blockIdx.y << 6) + (blockIdx.z << 10);
    const int xcd = lin & 7, s = lin >> 3;
    const int g   = (xcd << 2) | (s >> 6);   // 0..31 (h,b) group
    const int u   = s & 63;
    const int bx  = 63 - u;                  // LPT: longest blocks first
    const int h   = g & 15;
    const int b   = g >> 4;
    const int q0  = bx * 32;

    const bf16* qc_bh  = qc_g + ((size_t)(b * NH + h) * QL) * HD;
    const bf16* qp_bh  = qp_g + ((size_t)(b * NH + h) * QL) * HD;
    const bf16* k_bh   = k_g  + ((size_t)(b * NH + h) * KLEN) * HD;
    const bf16* v_bh   = v_g  + ((size_t)(b * NH + h) * KLEN) * HD;
    const bf16* kpos_h = kpos_g + (size_t)h * SPE * HD;

    __shared__ __align__(16) bf16 K_s [64 * 64];
    __shared__ __align__(16) bf16 Kp_s[96 * 64];
    __shared__ __align__(16) bf16 Vt_s[64 * 64];     // [d][k], chunk-swizzled
    __shared__ __align__(16) bf16 Pb_s[32 * 64];
    __shared__ float Sc_s[32][69];
    __shared__ float Pt_s[32][98];                   // read stride 97: free
    __shared__ float arow_s[32];

    const int t = threadIdx.x;
    const int w = t >> 6, lane = t & 63, lm = lane & 15, quad = lane >> 4;

    const int sr = t >> 3;            // softmax row
    const int sc = (t & 7) * 8;       // softmax col chunk
    const int vrr = t >> 3, vch = t & 7;   // V staging: k-pair 2*vrr, d-chunk vch
    const int vkc = vrr >> 2;         // k-chunk of this thread's V pair

    const int mtc = w & 1;            // content/PV m-tile
    const int ntc = (w >> 1) * 2;     // content/PV n-tile base
    const int mtp = w >> 1;           // pos m-tile
    const int ntp = (w & 1) * 3;      // pos n-tile base

    float m_run = NEG_INF, l_part = 0.0f;
    f32x4 accO[2] = {{0,0,0,0},{0,0,0,0}};
    u16x8 vv0, vv1;

    const int nkt = (bx >> 1) + 1;

    // ---- Q fragments: loop-invariant, straight global -> registers ----
    short8 aQc0, aQc1, aQp0, aQp1;
    {
        const bf16* qr = qc_bh + (size_t)(q0 + mtc * 16 + lm) * HD;
        aQc0 = *(const short8*)(qr + quad * 8);
        aQc1 = *(const short8*)(qr + (4 + quad) * 8);
        const bf16* pr = qp_bh + (size_t)(q0 + mtp * 16 + lm) * HD;
        aQp0 = *(const short8*)(pr + quad * 8);
        aQp1 = *(const short8*)(pr + (4 + quad) * 8);
    }

    // ---- prologue: stage tile 0 ----
#pragma unroll
    for (int i = 0; i < 2; i++) {
        int c = i * 256 + t, r = c >> 3, ch = c & 7, gc = ch ^ (r & 7);
        llds16(k_bh + (size_t)r * HD + gc * 8, K_s + (c & ~63) * 8);
    }
    {
        const int s0 = 2016 - q0;
#pragma unroll
        for (int i = 0; i < 3; i++) {
            int c = i * 256 + t, r = c >> 3, ch = c & 7, gc = ch ^ (r & 7);
            llds16(kpos_h + (size_t)(s0 + r) * HD + gc * 8, Kp_s + (c & ~63) * 8);
        }
    }
    vv0 = *(const u16x8*)&v_bh[(size_t)(2 * vrr)     * HD + vch * 8];
    vv1 = *(const u16x8*)&v_bh[(size_t)(2 * vrr + 1) * HD + vch * 8];

    for (int kt = 0; kt < nkt; kt++) {
        const int k0 = kt * 64;

        __syncthreads();   // A: DMA drained; prev-iter PV reads of Vt done

        // ---- transpose-write V: slot = kc ^ (d>>3) ^ (d&7) ----
        {
            const int off = (2 * vrr) & 7;
#pragma unroll
            for (int j = 0; j < 8; j++) {
                unsigned int pair = (unsigned int)vv0[j] | ((unsigned int)vv1[j] << 16);
                int slot = vkc ^ vch ^ j;           // d>>3 = vch, d&7 = j
                *(unsigned int*)&Vt_s[(vch * 8 + j) * 64 + slot * 8 + off] = pair;
            }
        }

        // ---- content scores S = Qc K^T ----
        {
#pragma unroll
            for (int n = 0; n < 2; n++) {
                int rowB = (ntc + n) * 16 + lm;
                short8 b0 = *(const short8*)&K_s[rowB * 64 + ((quad)     ^ (rowB & 7)) * 8];
                short8 b1 = *(const short8*)&K_s[rowB * 64 + ((4 + quad) ^ (rowB & 7)) * 8];
                f32x4 acc = {0, 0, 0, 0};
                acc = __builtin_amdgcn_mfma_f32_16x16x32_bf16(aQc0, b0, acc, 0, 0, 0);
                acc = __builtin_amdgcn_mfma_f32_16x16x32_bf16(aQc1, b1, acc, 0, 0, 0);
#pragma unroll
                for (int r = 0; r < 4; r++)
                    Sc_s[mtc * 16 + quad * 4 + r][(ntc + n) * 16 + lm] = acc[r];
            }
        }
        // ---- pos band P~ = Qp Kp^T ----
        {
#pragma unroll
            for (int n = 0; n < 3; n++) {
                int rowB = (ntp + n) * 16 + lm;
                short8 b0 = *(const short8*)&Kp_s[rowB * 64 + ((quad)     ^ (rowB & 7)) * 8];
                short8 b1 = *(const short8*)&Kp_s[rowB * 64 + ((4 + quad) ^ (rowB & 7)) * 8];
                f32x4 acc = {0, 0, 0, 0};
                acc = __builtin_amdgcn_mfma_f32_16x16x32_bf16(aQp0, b0, acc, 0, 0, 0);
                acc = __builtin_amdgcn_mfma_f32_16x16x32_bf16(aQp1, b1, acc, 0, 0, 0);
#pragma unroll
                for (int r = 0; r < 4; r++)
                    Pt_s[mtp * 16 + quad * 4 + r][(ntp + n) * 16 + lm] = acc[r];
            }
        }

        __syncthreads();   // B: scores in LDS; K/Kp/Vt reads+writes done

        // ---- prefetch tile kt+1: issued BEFORE softmax, drains at next A ----
        if (kt + 1 < nkt) {
            const int k0n = k0 + 64;
            const int s0n = k0n - q0 + 2016;
#pragma unroll
            for (int i = 0; i < 2; i++) {
                int c = i * 256 + t, r = c >> 3, ch = c & 7, gc = ch ^ (r & 7);
                llds16(k_bh + (size_t)(k0n + r) * HD + gc * 8, K_s + (c & ~63) * 8);
            }
#pragma unroll
            for (int i = 0; i < 3; i++) {
                int c = i * 256 + t, r = c >> 3, ch = c & 7, gc = ch ^ (r & 7);
                llds16(kpos_h + (size_t)(s0n + r) * HD + gc * 8, Kp_s + (c & ~63) * 8);
            }
            vv0 = *(const u16x8*)&v_bh[(size_t)(k0n + 2 * vrr)     * HD + vch * 8];
            vv1 = *(const u16x8*)&v_bh[(size_t)(k0n + 2 * vrr + 1) * HD + vch * 8];
        }

        // ---- online softmax, exp2 domain: defer-max + deferred sum ----
        {
            float p[8];
            float pmax = NEG_INF;
#pragma unroll
            for (int j = 0; j < 8; j++) {
                int col = sc + j;
                float sv = (Sc_s[sr][col] + Pt_s[sr][col - sr + 31]) * SCL2;
                if (k0 + col > q0 + sr) sv = NEG_INF;
                p[j] = sv;
                pmax = fmaxf(pmax, sv);
            }
            float alpha = 1.0f;
            if (!__all(pmax <= m_run + 11.5f)) {
                float mx = pmax;
                mx = fmaxf(mx, __shfl_xor(mx, 1, 8));
                mx = fmaxf(mx, __shfl_xor(mx, 2, 8));
                mx = fmaxf(mx, __shfl_xor(mx, 4, 8));
                float mnew = fmaxf(m_run, mx);
                alpha = __builtin_amdgcn_exp2f(m_run - mnew);
                m_run = mnew;
            }
            float ls = 0.0f;
#pragma unroll
            for (int j = 0; j < 8; j++) {
                p[j] = __builtin_amdgcn_exp2f(p[j] - m_run);
                ls += p[j];
            }
            l_part = l_part * alpha + ls;
            if ((t & 7) == 0) arow_s[sr] = alpha;
            short8 pv;
#pragma unroll
            for (int j = 0; j < 8; j++) { bf16 x = (bf16)p[j]; pv[j] = *(short*)&x; }
            *(short8*)&Pb_s[sr * 64 + ((t & 7) ^ (sr & 7)) * 8] = pv;
        }

        // ---- C: LIGHT barrier — wait LDS ops only; keep prefetch DMA in flight
        asm volatile("s_waitcnt lgkmcnt(0)" ::: "memory");
        __builtin_amdgcn_s_barrier();
        __builtin_amdgcn_sched_barrier(0);

        // ---- O update: acc = alpha*acc + P V ----
        {
            float al[4];
#pragma unroll
            for (int r = 0; r < 4; r++) al[r] = arow_s[mtc * 16 + quad * 4 + r];
            int rowA = mtc * 16 + lm;
            short8 a0 = *(const short8*)&Pb_s[rowA * 64 + ((quad)     ^ (rowA & 7)) * 8];
            short8 a1 = *(const short8*)&Pb_s[rowA * 64 + ((4 + quad) ^ (rowA & 7)) * 8];
#pragma unroll
            for (int n = 0; n < 2; n++) {
                int d = (ntc + n) * 16 + lm;
                int ds = (d >> 3) ^ (d & 7);
                short8 b0 = *(const short8*)&Vt_s[d * 64 + ((quad     ^ ds)) * 8];
                short8 b1 = *(const short8*)&Vt_s[d * 64 + (((4 + quad) ^ ds)) * 8];
#pragma unroll
                for (int r = 0; r < 4; r++) accO[n][r] *= al[r];
                accO[n] = __builtin_amdgcn_mfma_f32_16x16x32_bf16(a0, b0, accO[n], 0, 0, 0);
                accO[n] = __builtin_amdgcn_mfma_f32_16x16x32_bf16(a1, b1, accO[n], 0, 0, 0);
            }
        }
    }

    // ---- epilogue: reduce per-thread partial l across the 8 threads/row ----
    l_part += __shfl_xor(l_part, 1, 8);
    l_part += __shfl_xor(l_part, 2, 8);
    l_part += __shfl_xor(l_part, 4, 8);

    __syncthreads();                       // protect arow before l broadcast
    if ((t & 7) == 0) arow_s[sr] = l_part;
    __syncthreads();

    float linv[4];
#pragma unroll
    for (int r = 0; r < 4; r++) linv[r] = 1.0f / arow_s[mtc * 16 + quad * 4 + r];
#pragma unroll
    for (int n = 0; n < 2; n++) {
#pragma unroll
        for (int r = 0; r < 4; r++) {
            int row = mtc * 16 + quad * 4 + r;
            ao[(((size_t)(q0 + row) * BATCH + b) * EMB) + h * HD + (ntc + n) * 16 + lm] =
                (bf16)(accO[n][r] * linv[r]);
        }
    }
}

// ---------------------------------------------------------------------------
extern "C" void kernel_launch(void* const* d_in, const int* in_sizes, int n_in,
                              void* d_out, int out_size, void* d_ws, size_t ws_size,
                              hipStream_t stream)
{
    const void* query = d_in[0];
    const void* key   = d_in[1];
    const void* value = d_in[2];
    const void* pe    = d_in[3];
    const void* w_q   = d_in[4];
    const void* w_k   = d_in[5];
    const void* w_v   = d_in[6];
    const void* w_kp  = d_in[7];
    const void* w_out = d_in[8];
    const void* cb    = d_in[9];
    const void* pb    = d_in[10];
    float* out = (float*)d_out;

    const size_t SLAB = 4194304;
    bf16* qc   = (bf16*)d_ws;          // S0
    bf16* qp   = qc + SLAB;            // S1
    bf16* kw   = qp + SLAB;            // S2
    bf16* vw   = kw + SLAB;            // S3
    bf16* kpos = vw + SLAB;            // S4
    bf16* ao   = kpos + SLAB;          // S5 (attention output)
    bf16* wqb  = ao + SLAB;            // S6: wq,wk,wv,wkp,wo,cb,pb

    dim3 blk(256);

    conv_w<<<dim3(1281), blk, 0, stream>>>(w_q, w_k, w_v, w_kp, w_out, cb, pb, wqb);

    // fused projections reading RAW inputs: q (2 outs + biases), k, v, pe
    // 64x128 tiles: 64 M-tiles x 8 N-tiles x 4 modes = 2048 blocks (6/CU)
    gemm_big<<<dim3(2048), blk, 0, stream>>>(
        query, key, value, pe, nullptr, wqb, qc, qp, kw, vw, kpos, nullptr, 0);

    attn_mfma<<<dim3(64, NH, BATCH), blk, 0, stream>>>(qc, qp, kw, vw, kpos, ao);

    // output projection (mode 4): ao @ wo^T -> f32 out (512 blocks)
    gemm_big<<<dim3(512), blk, 0, stream>>>(
        query, key, value, pe, ao, wqb, qc, qp, kw, vw, kpos, out, 4);
}